// Round 3
// baseline (774.593 us; speedup 1.0000x reference)
//
#include <hip/hip_runtime.h>
#include <stdint.h>

#define BATCH   8
#define NPTS    8192
#define SCH     1024
#define KNN     32
#define TOPC    5
#define MAXIT   16

typedef unsigned long long ull;
typedef uint16_t u16;
typedef uint8_t  u8;
typedef float vf2 __attribute__((ext_vector_type(2)));
typedef float vf4 __attribute__((ext_vector_type(4)));

// sentinel: unpacks to +inf d2, never enters top-32
#define SENTKEY ((((ull)0x7F800000u) << 13) | 0x1FFFull)

// ---------------------------------------------------------------------------
// Exact d2: separate mul/add roundings (no FMA), order ((dx2+dy2)+dz2) = numpy.
// ---------------------------------------------------------------------------
__device__ __forceinline__ float d2_exact(vf4 q, vf4 p) {
#pragma clang fp contract(off)
    vf2 d = q.xy - p.xy;
    vf2 s = d * d;
    float dz = q.z - p.z;
    float sz = dz * dz;
    return (s.x + s.y) + sz;
}

__device__ __forceinline__ void insert_top4(ull key, ull& k0, ull& k1, ull& k2,
                                            ull& k3, float& th) {
    if (key < k3) {
        k3 = key;
        { bool c = k3 < k2; ull mn = c ? k3 : k2, mx = c ? k2 : k3; k2 = mn; k3 = mx; }
        { bool c = k2 < k1; ull mn = c ? k2 : k1, mx = c ? k1 : k2; k1 = mn; k2 = mx; }
        { bool c = k1 < k0; ull mn = c ? k1 : k0, mx = c ? k0 : k1; k0 = mn; k1 = mx; }
        th = __uint_as_float((uint32_t)(k3 >> 13));
    }
}

// scan 128 strided points per lane, keep sorted top-4 (unique 45-bit keys)
__device__ __forceinline__ void scan_top4(const vf4* __restrict__ P, vf4 q, int lane,
                                          ull& k0, ull& k1, ull& k2, ull& k3) {
    k0 = k1 = k2 = k3 = SENTKEY;
    float th = __builtin_inff();
    const vf4* __restrict__ L = P + lane;
    vf4 b0 = L[0], b1 = L[64], b2 = L[128], b3 = L[192];
#pragma unroll 4
    for (int t = 0; t < 128; t += 4) {
        vf4 n0 = b0, n1 = b1, n2 = b2, n3 = b3;
        if (t + 4 < 128) {
            const vf4* __restrict__ Q = L + (size_t)(t + 4) * 64;
            n0 = Q[0]; n1 = Q[64]; n2 = Q[128]; n3 = Q[192];
        }
        {
            float d2 = d2_exact(q, b0);
            if (d2 <= th)
                insert_top4(((ull)__float_as_uint(d2) << 13) | (uint32_t)(lane + t * 64),
                            k0, k1, k2, k3, th);
        }
        {
            float d2 = d2_exact(q, b1);
            if (d2 <= th)
                insert_top4(((ull)__float_as_uint(d2) << 13) | (uint32_t)(lane + (t + 1) * 64),
                            k0, k1, k2, k3, th);
        }
        {
            float d2 = d2_exact(q, b2);
            if (d2 <= th)
                insert_top4(((ull)__float_as_uint(d2) << 13) | (uint32_t)(lane + (t + 2) * 64),
                            k0, k1, k2, k3, th);
        }
        {
            float d2 = d2_exact(q, b3);
            if (d2 <= th)
                insert_top4(((ull)__float_as_uint(d2) << 13) | (uint32_t)(lane + (t + 3) * 64),
                            k0, k1, k2, k3, th);
        }
        b0 = n0; b1 = n1; b2 = n2; b3 = n3;
    }
}

// bitonic helpers
__device__ __forceinline__ ull cx(ull v, int xl, bool keepmin) {
    ull o = (ull)__shfl_xor((unsigned long long)v, xl, 64);
    return ((v < o) == keepmin) ? v : o;
}
__device__ __forceinline__ void cswap(ull& a, ull& b, bool up) {
    bool lt = a < b;
    ull mn = lt ? a : b, mx = lt ? b : a;
    a = up ? mn : mx;
    b = up ? mx : mn;
}

// ---------------------------------------------------------------------------
// Rare fallback (~11%/query): serial extraction with refill (exact).
// ---------------------------------------------------------------------------
__device__ __attribute__((noinline)) int serial_topk(const vf4* __restrict__ P, vf4 q,
                                                     int lane) {
    ull k0 = SENTKEY, k1 = SENTKEY, k2 = SENTKEY, k3 = SENTKEY;
    float th = __builtin_inff();
    for (int t = 0; t < 128; ++t) {
        int p = lane + t * 64;
        float d2 = d2_exact(q, P[p]);
        if (d2 <= th)
            insert_top4(((ull)__float_as_uint(d2) << 13) | (uint32_t)p, k0, k1, k2, k3, th);
    }
    ull em0 = 0ull, em1 = 0ull;
    int cnt = 4;
    int my_ind = 0;
    for (int r = 0; r < KNN; ++r) {
        ull gmin = k0;
#pragma unroll
        for (int off = 32; off; off >>= 1) {
            ull o = (ull)__shfl_xor((unsigned long long)gmin, off, 64);
            gmin = o < gmin ? o : gmin;
        }
        int widx = (int)(gmin & 0x1FFFull);
        if (lane == r) my_ind = widx;
        if (k0 == gmin) {
            int tt = widx >> 6;
            if (tt < 64) em0 |= 1ull << tt;
            else         em1 |= 1ull << (tt - 64);
            k0 = k1; k1 = k2; k2 = k3; k3 = SENTKEY;
            if (--cnt == 0) {
                k0 = k1 = k2 = k3 = SENTKEY;
                float th2 = __builtin_inff();
                for (int t2 = 0; t2 < 128; ++t2) {
                    bool ex = (t2 < 64) ? ((em0 >> t2) & 1ull) : ((em1 >> (t2 - 64)) & 1ull);
                    if (ex) continue;
                    int p = lane + t2 * 64;
                    float d2 = d2_exact(q, P[p]);
                    if (d2 <= th2)
                        insert_top4(((ull)__float_as_uint(d2) << 13) | (uint32_t)p,
                                    k0, k1, k2, k3, th2);
                }
                cnt = 4;
            }
        }
    }
    return my_ind;
}

// ---------------------------------------------------------------------------
// Prep: xyz (B,N,3) -> padded float4 SoA
// ---------------------------------------------------------------------------
__global__ __launch_bounds__(256) void prep_kernel(const float* __restrict__ xyz,
                                                   vf4* __restrict__ pc4) {
    int i = (int)(blockIdx.x * blockDim.x + threadIdx.x);
    if (i < BATCH * NPTS) {
        vf4 v;
        v.x = xyz[(size_t)i * 3 + 0];
        v.y = xyz[(size_t)i * 3 + 1];
        v.z = xyz[(size_t)i * 3 + 2];
        v.w = 0.f;
        pc4[i] = v;
    }
}

// ---------------------------------------------------------------------------
// Step kernel: one wave per query. Queries 0..B*N-1 are cloud points (the
// memoized step table); queries B*N.. are the 8192 center (it=0) queries.
// Each wave computes the exact ordered top-32, in_top flag, and move target.
// Fully parallel: no convergence loop -> no tail, full occupancy.
// ---------------------------------------------------------------------------
__global__ __launch_bounds__(256) void step_kernel(
    const vf4* __restrict__ pc4, const float* __restrict__ center,
    u16* __restrict__ ind_pt, u16* __restrict__ next_pt, u8* __restrict__ intop_pt,
    u16* __restrict__ ind_c,  u16* __restrict__ next_c,  u8* __restrict__ intop_c) {
    const int wv = (int)((blockIdx.x * blockDim.x + threadIdx.x) >> 6);
    const int lane = (int)(threadIdx.x & 63);
    const int w = (int)(threadIdx.x >> 6);

    __shared__ vf4 nbh[4][KNN];

    const bool isC = (wv >= BATCH * NPTS);
    int b, qi = 0, cidx = 0;
    vf4 q;
    const vf4* __restrict__ P;
    if (!isC) {
        b = wv >> 13;             // / NPTS
        qi = wv & (NPTS - 1);
        P = pc4 + (size_t)b * NPTS;
        q = P[qi];
    } else {
        cidx = wv - BATCH * NPTS; // chain id 0..8191
        b = cidx >> 10;
        P = pc4 + (size_t)b * NPTS;
        q.x = center[(size_t)cidx * 3 + 0];
        q.y = center[(size_t)cidx * 3 + 1];
        q.z = center[(size_t)cidx * 3 + 2];
        q.w = 0.f;
    }

    // ---- KNN: per-lane top-4 then wave bitonic sort of 256 candidates ----
    ull k0, k1, k2, k3;
    scan_top4(P, q, lane, k0, k1, k2, k3);
    const ull prek3 = k3;

    const bool odd = (lane & 1) != 0;
    ull a0 = odd ? k3 : k0;
    ull a1 = odd ? k2 : k1;
    ull a2 = odd ? k1 : k2;
    ull a3 = odd ? k0 : k3;
#pragma unroll
    for (int kk = 8; kk <= 256; kk <<= 1) {
        const bool up = (lane & (kk >> 2)) == 0;
#pragma unroll
        for (int d = kk >> 1; d >= 4; d >>= 1) {
            const int xl = d >> 2;
            const bool keepmin = (up == ((lane & xl) == 0));
            a0 = cx(a0, xl, keepmin);
            a1 = cx(a1, xl, keepmin);
            a2 = cx(a2, xl, keepmin);
            a3 = cx(a3, xl, keepmin);
        }
        cswap(a0, a2, up); cswap(a1, a3, up);
        cswap(a0, a1, up); cswap(a2, a3, up);
    }
    // rank r lives at lane r>>2, reg r&3; tau = rank-31 key
    const ull tau = (ull)__shfl((unsigned long long)a3, 7, 64);
    const ull bad = __ballot(prek3 < tau);
    int my_ind;
    if (bad != 0ull) {
        my_ind = serial_topk(P, q, lane);  // a lane may have truncated a winner
    } else {
        const int src = lane >> 2;
        const uint32_t lo0 = (uint32_t)__shfl((int)(uint32_t)a0, src, 64);
        const uint32_t lo1 = (uint32_t)__shfl((int)(uint32_t)a1, src, 64);
        const uint32_t lo2 = (uint32_t)__shfl((int)(uint32_t)a2, src, 64);
        const uint32_t lo3 = (uint32_t)__shfl((int)(uint32_t)a3, src, 64);
        const int sel = lane & 3;
        uint32_t lo = (sel == 0) ? lo0 : (sel == 1) ? lo1 : (sel == 2) ? lo2 : lo3;
        my_ind = (int)(lo & 0x1FFFu);
    }

    // ---- centroid: stage 32 ordered neighbors to LDS, sequential fold ----
    vf4 myp = q;
    if (lane < KNN) {
        myp = P[my_ind];
        nbh[w][lane] = myp;
    }
    __asm__ volatile("s_waitcnt lgkmcnt(0)" ::: "memory");
    float sx = 0.f, sy = 0.f, sz = 0.f;
#pragma unroll
    for (int j = 0; j < KNN; ++j) {
        vf4 pj = nbh[w][j];
        sx = __fadd_rn(sx, pj.x);
        sy = __fadd_rn(sy, pj.y);
        sz = __fadd_rn(sz, pj.z);
    }
    const float gx = __fmul_rn(sx, 0.03125f);
    const float gy = __fmul_rn(sy, 0.03125f);
    const float gz = __fmul_rn(sz, 0.03125f);

    // ---- per-neighbor distance to centroid (post-sqrt ordering) ----
    float dj = __builtin_inff();
    if (lane < KNN) {
        const float dx = __fsub_rn(myp.x, gx);
        const float dy = __fsub_rn(myp.y, gy);
        const float dz = __fsub_rn(myp.z, gz);
        dj = sqrtf(__fadd_rn(__fadd_rn(__fmul_rn(dx, dx), __fmul_rn(dy, dy)),
                             __fmul_rn(dz, dz)));
    }
    const uint32_t db = __float_as_uint(dj);  // nonneg: bit order == fp order
    const uint32_t d0 = (uint32_t)__shfl((int)db, 0, 64);
    const ull bal = __ballot(db < d0);
    const bool in_top = (__popcll(bal) <= TOPC - 1);

    // move target: lexicographic argmin of (dist, j) via 32-bit butterfly
    uint32_t m = db;
#pragma unroll
    for (int off = 32; off; off >>= 1) {
        uint32_t o = (uint32_t)__shfl_xor((int)m, off, 64);
        m = o < m ? o : m;
    }
    const ull balm = __ballot(db == m);
    const int jm = __ffsll((unsigned long long)balm) - 1;
    const int nidx = __shfl(my_ind, jm, 64);

    // ---- write step-table entry ----
    if (!isC) {
        const size_t row = (size_t)b * NPTS + qi;
        if (lane < KNN) ind_pt[row * KNN + lane] = (u16)my_ind;
        if (lane == 0) {
            next_pt[row] = (u16)nidx;
            intop_pt[row] = in_top ? 1 : 0;
        }
    } else {
        const size_t row = (size_t)cidx;
        if (lane < KNN) ind_c[row * KNN + lane] = (u16)my_ind;
        if (lane == 0) {
            next_c[row] = (u16)nidx;
            intop_c[row] = in_top ? 1 : 0;
        }
    }
}

// ---------------------------------------------------------------------------
// Chase: one thread per chain follows the precomputed step table (<=16 hops).
// fidx = -1 means converged at it=0 (result is the original center/idx).
// ---------------------------------------------------------------------------
__global__ __launch_bounds__(256) void chase_kernel(
    const u16* __restrict__ next_pt, const u8* __restrict__ intop_pt,
    const u16* __restrict__ next_c,  const u8* __restrict__ intop_c,
    int* __restrict__ conv_ws, int* __restrict__ fidx_ws) {
    const int ch = (int)(blockIdx.x * blockDim.x + threadIdx.x);
    if (ch >= BATCH * SCH) return;
    const int b = ch >> 10;
    const size_t base = (size_t)b * NPTS;
    int conv, fidx;
    if (intop_c[ch]) {
        conv = 0;
        fidx = -1;
    } else {
        int cur = (int)next_c[ch];
        conv = MAXIT;
        for (int it = 1; it < MAXIT; ++it) {
            if (intop_pt[base + cur]) { conv = it; break; }
            cur = (int)next_pt[base + cur];
        }
        fidx = cur;
    }
    conv_ws[ch] = conv;
    fidx_ws[ch] = fidx;
}

// ---------------------------------------------------------------------------
// Order: stable rank by (conv, s); gather outputs from tables.
// ---------------------------------------------------------------------------
__global__ __launch_bounds__(1024) void order_kernel(
    const vf4* __restrict__ pc4, const float* __restrict__ center,
    const int* __restrict__ idx_in,
    const u16* __restrict__ ind_pt, const u16* __restrict__ ind_c,
    const int* __restrict__ conv_ws, const int* __restrict__ fidx_ws,
    float* __restrict__ out) {
    const int b = (int)blockIdx.x;
    const int s = (int)threadIdx.x;
    const int w = s >> 6, l = s & 63;
    __shared__ int wavecnt[16][MAXIT + 1];
    __shared__ int binbase[MAXIT + 1];
    const size_t ch = (size_t)b * SCH + s;
    const int c = conv_ws[ch];
    int rw = 0;
#pragma unroll
    for (int v = 0; v <= MAXIT; ++v) {
        ull bal = __ballot(c == v);
        if (l == 0) wavecnt[w][v] = (int)__popcll(bal);
        if (c == v) rw = (int)__popcll(bal & ((1ull << l) - 1ull));
    }
    __syncthreads();
    if (s == 0) {
        int acc = 0;
        for (int v = 0; v <= MAXIT; ++v) {
            int t = 0;
            for (int w2 = 0; w2 < 16; ++w2) t += wavecnt[w2][v];
            binbase[v] = acc;
            acc += t;
        }
    }
    __syncthreads();
    int pos = binbase[c] + rw;
    for (int w2 = 0; w2 < w; ++w2) pos += wavecnt[w2][c];

    float* __restrict__ C  = out;                              // (B,S,3)
    float* __restrict__ I1 = out + (size_t)BATCH * SCH * 3;    // (B,S)
    float* __restrict__ I2 = I1 + (size_t)BATCH * SCH;         // (B,S,K)
    const size_t o = (size_t)b * SCH + pos;

    const int f = fidx_ws[ch];
    if (f < 0) {  // converged at it=0: original center coords + input idx
        C[o * 3 + 0] = center[ch * 3 + 0];
        C[o * 3 + 1] = center[ch * 3 + 1];
        C[o * 3 + 2] = center[ch * 3 + 2];
        I1[o] = (float)idx_in[ch];
#pragma unroll
        for (int k = 0; k < KNN; ++k)
            I2[o * KNN + k] = (float)ind_c[ch * KNN + k];
    } else {
        vf4 p = pc4[(size_t)b * NPTS + f];
        C[o * 3 + 0] = p.x;
        C[o * 3 + 1] = p.y;
        C[o * 3 + 2] = p.z;
        I1[o] = (float)f;
        const size_t row = ((size_t)b * NPTS + f) * KNN;
#pragma unroll
        for (int k = 0; k < KNN; ++k)
            I2[o * KNN + k] = (float)ind_pt[row + k];
    }
}

extern "C" void kernel_launch(void* const* d_in, const int* in_sizes, int n_in,
                              void* d_out, int out_size, void* d_ws, size_t ws_size,
                              hipStream_t stream) {
    const float* xyz    = (const float*)d_in[0];  // (8,8192,3) f32
    const float* center = (const float*)d_in[1];  // (8,1024,3) f32
    const int*   idx_in = (const int*)d_in[2];    // (8,1024)   i32
    float* out = (float*)d_out;

    // workspace layout (~5.8 MB)
    char* wp = (char*)d_ws;
    vf4* pc4 = (vf4*)wp;          wp += (size_t)BATCH * NPTS * sizeof(vf4);   // 1 MB
    u16* ind_pt = (u16*)wp;       wp += (size_t)BATCH * NPTS * KNN * 2;       // 4 MB
    u16* ind_c = (u16*)wp;        wp += (size_t)BATCH * SCH * KNN * 2;        // 512 KB
    u16* next_pt = (u16*)wp;      wp += (size_t)BATCH * NPTS * 2;             // 128 KB
    u16* next_c = (u16*)wp;       wp += (size_t)BATCH * SCH * 2;              // 16 KB
    u8* intop_pt = (u8*)wp;       wp += (size_t)BATCH * NPTS;                 // 64 KB
    u8* intop_c = (u8*)wp;        wp += (size_t)BATCH * SCH;                  // 8 KB
    int* conv_ws = (int*)wp;      wp += (size_t)BATCH * SCH * 4;              // 32 KB
    int* fidx_ws = (int*)wp;

    prep_kernel<<<(BATCH * NPTS + 255) / 256, 256, 0, stream>>>(xyz, pc4);

    const int nq = BATCH * NPTS + BATCH * SCH;      // 73728 independent queries
    step_kernel<<<nq * 64 / 256, 256, 0, stream>>>(pc4, center,
                                                   ind_pt, next_pt, intop_pt,
                                                   ind_c, next_c, intop_c);
    chase_kernel<<<(BATCH * SCH + 255) / 256, 256, 0, stream>>>(
        next_pt, intop_pt, next_c, intop_c, conv_ws, fidx_ws);
    order_kernel<<<BATCH, SCH, 0, stream>>>(pc4, center, idx_in,
                                            ind_pt, ind_c, conv_ws, fidx_ws, out);
}

// Round 4
// 233.841 us; speedup vs baseline: 3.3125x; 3.3125x over previous
//
#include <hip/hip_runtime.h>
#include <stdint.h>

#define BATCH   8
#define NPTS    8192
#define SCH     1024
#define KNN     32
#define TOPC    5
#define MAXIT   16
#define NCELL   4096     // 16^3 morton cells
#define NGRP    128      // groups of 64 per batch

typedef unsigned long long ull;
typedef uint16_t u16;
typedef float vf2 __attribute__((ext_vector_type(2)));
typedef float vf4 __attribute__((ext_vector_type(4)));

// sentinel: unpacks to +inf d2, never enters top-32
#define SENTKEY ((((ull)0x7F800000u) << 13) | 0x1FFFull)

// ---------------------------------------------------------------------------
// Exact d2: separate mul/add roundings (no FMA), order ((dx2+dy2)+dz2) = numpy.
// ---------------------------------------------------------------------------
__device__ __forceinline__ float d2_exact(vf4 q, vf4 p) {
#pragma clang fp contract(off)
    vf2 d = q.xy - p.xy;
    vf2 s = d * d;
    float dz = q.z - p.z;
    float sz = dz * dz;
    return (s.x + s.y) + sz;
}

__device__ __forceinline__ void insert_top4(ull key, ull& k0, ull& k1, ull& k2,
                                            ull& k3, float& th) {
    if (key < k3) {
        k3 = key;
        { bool c = k3 < k2; ull mn = c ? k3 : k2, mx = c ? k2 : k3; k2 = mn; k3 = mx; }
        { bool c = k2 < k1; ull mn = c ? k2 : k1, mx = c ? k1 : k2; k1 = mn; k2 = mx; }
        { bool c = k1 < k0; ull mn = c ? k1 : k0, mx = c ? k0 : k1; k0 = mn; k1 = mx; }
        th = __uint_as_float((uint32_t)(k3 >> 13));
    }
}

__device__ __forceinline__ ull wave_min_u64(ull k) {
#pragma unroll
    for (int off = 32; off; off >>= 1) {
        ull o = (ull)__shfl_xor((unsigned long long)k, off, 64);
        k = o < k ? o : k;
    }
    return k;
}
__device__ __forceinline__ ull wave_max_u64(ull k) {
#pragma unroll
    for (int off = 32; off; off >>= 1) {
        ull o = (ull)__shfl_xor((unsigned long long)k, off, 64);
        k = o > k ? o : k;
    }
    return k;
}

// conservative (under-estimated) squared min distance from q to group bbox
__device__ __forceinline__ float bbox_mind2(vf4 q, vf4 c, vf4 h) {
    float dx = fmaxf(fabsf(q.x - c.x) - h.x, 0.f);
    float dy = fmaxf(fabsf(q.y - c.y) - h.y, 0.f);
    float dz = fmaxf(fabsf(q.z - c.z) - h.z, 0.f);
    return (dx * dx + dy * dy + dz * dz) * 0.9999f;
}

// bitonic helpers
__device__ __forceinline__ ull cx(ull v, int xl, bool keepmin) {
    ull o = (ull)__shfl_xor((unsigned long long)v, xl, 64);
    return ((v < o) == keepmin) ? v : o;
}
__device__ __forceinline__ void cswap(ull& a, ull& b, bool up) {
    bool lt = a < b;
    ull mn = lt ? a : b, mx = lt ? b : a;
    a = up ? mn : mx;
    b = up ? mx : mn;
}

// morton cell id from point (16^3 over [-4,4], clamped)
__device__ __forceinline__ int cell_of(float x, float y, float z) {
    int cxi = min(15, max(0, (int)floorf((x + 4.0f) * 2.0f)));
    int cyi = min(15, max(0, (int)floorf((y + 4.0f) * 2.0f)));
    int czi = min(15, max(0, (int)floorf((z + 4.0f) * 2.0f)));
    uint32_t sx = (cxi & 1) | ((cxi & 2) << 2) | ((cxi & 4) << 4) | ((cxi & 8) << 6);
    uint32_t sy = (cyi & 1) | ((cyi & 2) << 2) | ((cyi & 4) << 4) | ((cyi & 8) << 6);
    uint32_t sz = (czi & 1) | ((czi & 2) << 2) | ((czi & 4) << 4) | ((czi & 8) << 6);
    return (int)(sx | (sy << 1) | (sz << 2));
}

// ---------------------------------------------------------------------------
// Rare fallback (~8%/query): exact serial extraction over the scanned groups.
// Tracks the source group of each kept key so refill can mask extractions.
// ---------------------------------------------------------------------------
__device__ __attribute__((noinline)) int serial_topk_masked(
    const vf4* __restrict__ Psort, vf4 q, int lane, ull sm0, ull sm1) {
    ull k0 = SENTKEY, k1 = SENTKEY, k2 = SENTKEY, k3 = SENTKEY;
    int s0 = 0, s1 = 0, s2 = 0, s3 = 0;
    float th = __builtin_inff();
    for (int gid = 0; gid < NGRP; ++gid) {
        bool sel = (gid < 64) ? ((sm0 >> gid) & 1ull) : ((sm1 >> (gid - 64)) & 1ull);
        if (!sel) continue;
        vf4 p = Psort[(gid << 6) + lane];
        float d2 = d2_exact(q, p);
        uint32_t oi = __float_as_uint(p.w);
        ull key = ((ull)__float_as_uint(d2) << 13) | oi;
        if (d2 <= th && key < k3) {
            k3 = key; s3 = gid;
            if (k3 < k2) { ull t = k2; k2 = k3; k3 = t; int ts = s2; s2 = s3; s3 = ts; }
            if (k2 < k1) { ull t = k1; k1 = k2; k2 = t; int ts = s1; s1 = s2; s2 = ts; }
            if (k1 < k0) { ull t = k0; k0 = k1; k1 = t; int ts = s0; s0 = s1; s1 = ts; }
            th = __uint_as_float((uint32_t)(k3 >> 13));
        }
    }
    ull em0 = 0ull, em1 = 0ull;
    int cnt = 4, my_ind = 0;
    for (int r = 0; r < KNN; ++r) {
        ull gmin = wave_min_u64(k0);
        int widx = (int)(gmin & 0x1FFFull);
        if (lane == r) my_ind = widx;
        if (k0 == gmin) {
            int g = s0;
            if (g < 64) em0 |= 1ull << g; else em1 |= 1ull << (g - 64);
            k0 = k1; k1 = k2; k2 = k3; k3 = SENTKEY;
            s0 = s1; s1 = s2; s2 = s3;
            if (--cnt == 0) {
                k0 = k1 = k2 = k3 = SENTKEY;
                float th2 = __builtin_inff();
                for (int gid = 0; gid < NGRP; ++gid) {
                    bool sel = (gid < 64) ? ((sm0 >> gid) & 1ull)
                                          : ((sm1 >> (gid - 64)) & 1ull);
                    bool ex = (gid < 64) ? ((em0 >> gid) & 1ull)
                                         : ((em1 >> (gid - 64)) & 1ull);
                    if (!sel || ex) continue;
                    vf4 p = Psort[(gid << 6) + lane];
                    float d2 = d2_exact(q, p);
                    uint32_t oi = __float_as_uint(p.w);
                    ull key = ((ull)__float_as_uint(d2) << 13) | oi;
                    if (d2 <= th2 && key < k3) {
                        k3 = key; s3 = gid;
                        if (k3 < k2) { ull t = k2; k2 = k3; k3 = t; int ts = s2; s2 = s3; s3 = ts; }
                        if (k2 < k1) { ull t = k1; k1 = k2; k2 = t; int ts = s1; s1 = s2; s2 = ts; }
                        if (k1 < k0) { ull t = k0; k0 = k1; k1 = t; int ts = s0; s0 = s1; s1 = ts; }
                        th2 = __uint_as_float((uint32_t)(k3 >> 13));
                    }
                }
                cnt = 4;
            }
        }
    }
    return my_ind;
}

// ---------------------------------------------------------------------------
// prep: xyz -> float4 SoA + per-cell histogram (counts pre-zeroed by memset)
// ---------------------------------------------------------------------------
__global__ __launch_bounds__(256) void prep_kernel(const float* __restrict__ xyz,
                                                   vf4* __restrict__ pc4,
                                                   int* __restrict__ counts) {
    int i = (int)(blockIdx.x * blockDim.x + threadIdx.x);
    if (i >= BATCH * NPTS) return;
    vf4 v;
    v.x = xyz[(size_t)i * 3 + 0];
    v.y = xyz[(size_t)i * 3 + 1];
    v.z = xyz[(size_t)i * 3 + 2];
    v.w = 0.f;
    pc4[i] = v;
    int b = i >> 13;
    atomicAdd(&counts[b * NCELL + cell_of(v.x, v.y, v.z)], 1);
}

// per-batch exclusive prefix sum of 4096 cell counts -> scatter cursors
__global__ __launch_bounds__(1024) void scan_kernel(const int* __restrict__ counts,
                                                    int* __restrict__ cursor) {
    int b = (int)blockIdx.x, tid = (int)threadIdx.x;
    __shared__ int part[1024];
    int base = b * NCELL + tid * 4;
    int v0 = counts[base], v1 = counts[base + 1], v2 = counts[base + 2], v3 = counts[base + 3];
    int s = v0 + v1 + v2 + v3;
    part[tid] = s;
    __syncthreads();
    for (int off = 1; off < 1024; off <<= 1) {
        int t = (tid >= off) ? part[tid - off] : 0;
        __syncthreads();
        part[tid] += t;
        __syncthreads();
    }
    int excl = part[tid] - s;
    cursor[base] = excl;
    cursor[base + 1] = excl + v0;
    cursor[base + 2] = excl + v0 + v1;
    cursor[base + 3] = excl + v0 + v1 + v2;
}

// scatter points into morton-sorted order; .w carries original index bits
__global__ __launch_bounds__(256) void scatter_kernel(const vf4* __restrict__ pc4,
                                                      int* __restrict__ cursor,
                                                      vf4* __restrict__ sortedP) {
    int i = (int)(blockIdx.x * blockDim.x + threadIdx.x);
    if (i >= BATCH * NPTS) return;
    vf4 v = pc4[i];
    int b = i >> 13, pi = i & (NPTS - 1);
    int c = cell_of(v.x, v.y, v.z);
    int pos = atomicAdd(&cursor[b * NCELL + c], 1);
    v.w = __uint_as_float((uint32_t)pi);
    sortedP[((size_t)b << 13) + pos] = v;
}

// per-group (64 sorted points) bbox center/half-extent
__global__ __launch_bounds__(256) void bbox_kernel(const vf4* __restrict__ sortedP,
                                                   vf4* __restrict__ bC,
                                                   vf4* __restrict__ bH) {
    int g = (int)((blockIdx.x * blockDim.x + threadIdx.x) >> 6);  // 0..B*NGRP-1
    int lane = (int)(threadIdx.x & 63);
    vf4 p = sortedP[((size_t)g << 6) + lane];
    float mnx = p.x, mxx = p.x, mny = p.y, mxy = p.y, mnz = p.z, mxz = p.z;
#pragma unroll
    for (int off = 32; off; off >>= 1) {
        mnx = fminf(mnx, __shfl_xor(mnx, off, 64));
        mxx = fmaxf(mxx, __shfl_xor(mxx, off, 64));
        mny = fminf(mny, __shfl_xor(mny, off, 64));
        mxy = fmaxf(mxy, __shfl_xor(mxy, off, 64));
        mnz = fminf(mnz, __shfl_xor(mnz, off, 64));
        mxz = fmaxf(mxz, __shfl_xor(mxz, off, 64));
    }
    if (lane == 0) {
        vf4 c, h;
        c.x = (mnx + mxx) * 0.5f; c.y = (mny + mxy) * 0.5f; c.z = (mnz + mxz) * 0.5f; c.w = 0.f;
        h.x = (mxx - mnx) * 0.5f; h.y = (mxy - mny) * 0.5f; h.z = (mxz - mnz) * 0.5f; h.w = 0.f;
        bC[g] = c;
        bH[g] = h;
    }
}

// ---------------------------------------------------------------------------
// Main refine: one wave per chain, bbox-pruned exact KNN per iteration
// ---------------------------------------------------------------------------
__global__ __launch_bounds__(256) void refine_kernel(
    const vf4* __restrict__ pc4, const vf4* __restrict__ sortedP,
    const vf4* __restrict__ bC, const vf4* __restrict__ bH,
    const float* __restrict__ center, const int* __restrict__ idx_in,
    float* __restrict__ pts_ws, int* __restrict__ idx_ws,
    int* __restrict__ grp_ws, int* __restrict__ conv_ws) {
    const int wv = (int)((blockIdx.x * blockDim.x + threadIdx.x) >> 6);
    const int lane = (int)(threadIdx.x & 63);
    const int w = (int)(threadIdx.x >> 6);
    if (wv >= BATCH * SCH) return;
    const int b = wv >> 10;
    const vf4* __restrict__ Porig = pc4 + ((size_t)b << 13);
    const vf4* __restrict__ Psort = sortedP + ((size_t)b << 13);

    __shared__ vf4 nbh[4][KNN];

    // bboxes are loop-invariant: lane owns groups (lane) and (64+lane)
    const int b128 = b << 7;
    const vf4 c0 = bC[b128 + lane], h0 = bH[b128 + lane];
    const vf4 c1 = bC[b128 + 64 + lane], h1 = bH[b128 + 64 + lane];

    const size_t ch = (size_t)wv;
    vf4 q;
    q.x = center[ch * 3 + 0];
    q.y = center[ch * 3 + 1];
    q.z = center[ch * 3 + 2];
    q.w = 0.f;
    int qidx = idx_in[ch];

    int conv = MAXIT;
    int my_ind = 0;

    for (int it = 0;; ++it) {
        // ---- group selection keys: (mind2_bits << 7) | gid, per-lane two ----
        float m0 = bbox_mind2(q, c0, h0);
        float m1 = bbox_mind2(q, c1, h1);
        ull r0 = ((ull)__float_as_uint(m0) << 7) | (uint32_t)lane;
        ull r1 = ((ull)__float_as_uint(m1) << 7) | (uint32_t)(64 + lane);

        ull k0 = SENTKEY, k1 = SENTKEY, k2 = SENTKEY, k3 = SENTKEY;
        float th = __builtin_inff();
        ull sm0 = 0ull, sm1 = 0ull;
        int nsc = 0;
        for (;;) {
            ull nk = wave_min_u64(r0 < r1 ? r0 : r1);
            if (nsc > 0) {
                if (nk == ~0ull) break;
                // sound upper bound B on current 32nd-smallest key:
                // max of 32 distinct pairwise-min candidates >= 32nd of union
                ull t = k0;
                ull o = (ull)__shfl_xor((unsigned long long)t, 32, 64);
                t = o < t ? o : t;
                ull B = wave_max_u64(t);
                float nm = __uint_as_float((uint32_t)(nk >> 7));
                float Bd = __uint_as_float((uint32_t)(B >> 13));
                if (nm > Bd) break;   // all remaining groups strictly beyond top-32
            }
            const int gid = (int)(nk & 127ull);
            if (gid < 64) {
                if (lane == gid) r0 = ~0ull;
                sm0 |= 1ull << gid;
            } else {
                if (lane == gid - 64) r1 = ~0ull;
                sm1 |= 1ull << (gid - 64);
            }
            vf4 p = Psort[(gid << 6) + lane];
            float d2 = d2_exact(q, p);
            uint32_t oi = __float_as_uint(p.w);
            if (d2 <= th)
                insert_top4(((ull)__float_as_uint(d2) << 13) | oi, k0, k1, k2, k3, th);
            ++nsc;
        }
        const ull prek3 = k3;

        // ---- wave bitonic sort of 256 candidates (sentinel-padded) ----
        const bool odd = (lane & 1) != 0;
        ull a0 = odd ? k3 : k0;
        ull a1 = odd ? k2 : k1;
        ull a2 = odd ? k1 : k2;
        ull a3 = odd ? k0 : k3;
#pragma unroll
        for (int kk = 8; kk <= 256; kk <<= 1) {
            const bool up = (lane & (kk >> 2)) == 0;
#pragma unroll
            for (int d = kk >> 1; d >= 4; d >>= 1) {
                const int xl = d >> 2;
                const bool keepmin = (up == ((lane & xl) == 0));
                a0 = cx(a0, xl, keepmin);
                a1 = cx(a1, xl, keepmin);
                a2 = cx(a2, xl, keepmin);
                a3 = cx(a3, xl, keepmin);
            }
            cswap(a0, a2, up); cswap(a1, a3, up);
            cswap(a0, a1, up); cswap(a2, a3, up);
        }
        // rank r lives at lane r>>2, reg r&3; tau = rank-31 key
        const ull tau = (ull)__shfl((unsigned long long)a3, 7, 64);
        const ull bad = __ballot(prek3 < tau);
        if (bad != 0ull) {
            my_ind = serial_topk_masked(Psort, q, lane, sm0, sm1);
        } else {
            const int src = lane >> 2;
            const uint32_t lo0 = (uint32_t)__shfl((int)(uint32_t)a0, src, 64);
            const uint32_t lo1 = (uint32_t)__shfl((int)(uint32_t)a1, src, 64);
            const uint32_t lo2 = (uint32_t)__shfl((int)(uint32_t)a2, src, 64);
            const uint32_t lo3 = (uint32_t)__shfl((int)(uint32_t)a3, src, 64);
            const int sel = lane & 3;
            uint32_t lo = (sel == 0) ? lo0 : (sel == 1) ? lo1 : (sel == 2) ? lo2 : lo3;
            my_ind = (int)(lo & 0x1FFFu);
        }

        if (it == MAXIT) break;  // final step's ind recorded; conv stays MAXIT

        // ---- centroid: stage 32 ordered neighbors to LDS, sequential fold ----
        vf4 myp = q;
        if (lane < KNN) {
            myp = Porig[my_ind];
            nbh[w][lane] = myp;
        }
        __asm__ volatile("s_waitcnt lgkmcnt(0)" ::: "memory");
        float sx = 0.f, sy = 0.f, sz = 0.f;
#pragma unroll
        for (int j = 0; j < KNN; ++j) {
            vf4 pj = nbh[w][j];
            sx = __fadd_rn(sx, pj.x);
            sy = __fadd_rn(sy, pj.y);
            sz = __fadd_rn(sz, pj.z);
        }
        const float gx = __fmul_rn(sx, 0.03125f);
        const float gy = __fmul_rn(sy, 0.03125f);
        const float gz = __fmul_rn(sz, 0.03125f);

        // ---- per-neighbor distance to centroid (post-sqrt ordering) ----
        float dj = __builtin_inff();
        if (lane < KNN) {
            const float dx = __fsub_rn(myp.x, gx);
            const float dy = __fsub_rn(myp.y, gy);
            const float dz = __fsub_rn(myp.z, gz);
            dj = sqrtf(__fadd_rn(__fadd_rn(__fmul_rn(dx, dx), __fmul_rn(dy, dy)),
                                 __fmul_rn(dz, dz)));
        }
        const uint32_t db = __float_as_uint(dj);  // nonneg: bit order == fp order
        const uint32_t d0 = (uint32_t)__shfl((int)db, 0, 64);
        const ull bal = __ballot(db < d0);
        if (__popcll(bal) <= TOPC - 1) { conv = it; break; }

        // move target: lexicographic argmin of (dist, j)
        uint32_t m = db;
#pragma unroll
        for (int off = 32; off; off >>= 1) {
            uint32_t o = (uint32_t)__shfl_xor((int)m, off, 64);
            m = o < m ? o : m;
        }
        const ull balm = __ballot(db == m);
        const int jm = __ffsll((unsigned long long)balm) - 1;
        const int nidx = __shfl(my_ind, jm, 64);
        qidx = nidx;
        q = Porig[nidx];
        q.w = 0.f;
    }

    if (lane < KNN) grp_ws[ch * KNN + lane] = my_ind;
    if (lane == 0) {
        pts_ws[ch * 3 + 0] = q.x;
        pts_ws[ch * 3 + 1] = q.y;
        pts_ws[ch * 3 + 2] = q.z;
        idx_ws[ch] = qidx;
        conv_ws[ch] = conv;
    }
}

// ---------------------------------------------------------------------------
// Order: stable rank by (conv, s) via 17-bin counting
// ---------------------------------------------------------------------------
__global__ __launch_bounds__(1024) void order_kernel(
    const float* __restrict__ pts_ws, const int* __restrict__ idx_ws,
    const int* __restrict__ grp_ws, const int* __restrict__ conv_ws,
    float* __restrict__ out) {
    const int b = (int)blockIdx.x;
    const int s = (int)threadIdx.x;
    const int w = s >> 6, l = s & 63;
    __shared__ int wavecnt[16][MAXIT + 1];
    __shared__ int binbase[MAXIT + 1];
    const size_t ch = (size_t)b * SCH + s;
    const int c = conv_ws[ch];
    int rw = 0;
#pragma unroll
    for (int v = 0; v <= MAXIT; ++v) {
        ull bal = __ballot(c == v);
        if (l == 0) wavecnt[w][v] = (int)__popcll(bal);
        if (c == v) rw = (int)__popcll(bal & ((1ull << l) - 1ull));
    }
    __syncthreads();
    if (s == 0) {
        int acc = 0;
        for (int v = 0; v <= MAXIT; ++v) {
            int t = 0;
            for (int w2 = 0; w2 < 16; ++w2) t += wavecnt[w2][v];
            binbase[v] = acc;
            acc += t;
        }
    }
    __syncthreads();
    int pos = binbase[c] + rw;
    for (int w2 = 0; w2 < w; ++w2) pos += wavecnt[w2][c];

    float* __restrict__ C  = out;                              // (B,S,3)
    float* __restrict__ I1 = out + (size_t)BATCH * SCH * 3;    // (B,S)
    float* __restrict__ I2 = I1 + (size_t)BATCH * SCH;         // (B,S,K)
    const size_t o = (size_t)b * SCH + pos;
    C[o * 3 + 0] = pts_ws[ch * 3 + 0];
    C[o * 3 + 1] = pts_ws[ch * 3 + 1];
    C[o * 3 + 2] = pts_ws[ch * 3 + 2];
    I1[o] = (float)idx_ws[ch];
#pragma unroll
    for (int k = 0; k < KNN; ++k) I2[o * KNN + k] = (float)grp_ws[ch * KNN + k];
}

extern "C" void kernel_launch(void* const* d_in, const int* in_sizes, int n_in,
                              void* d_out, int out_size, void* d_ws, size_t ws_size,
                              hipStream_t stream) {
    const float* xyz    = (const float*)d_in[0];  // (8,8192,3) f32
    const float* center = (const float*)d_in[1];  // (8,1024,3) f32
    const int*   idx_in = (const int*)d_in[2];    // (8,1024)   i32
    float* out = (float*)d_out;

    // workspace layout (~3.6 MB)
    char* wp = (char*)d_ws;
    vf4* pc4     = (vf4*)wp;  wp += (size_t)BATCH * NPTS * sizeof(vf4);   // 1 MB
    vf4* sortedP = (vf4*)wp;  wp += (size_t)BATCH * NPTS * sizeof(vf4);   // 1 MB
    vf4* bC      = (vf4*)wp;  wp += (size_t)BATCH * NGRP * sizeof(vf4);   // 16 KB
    vf4* bH      = (vf4*)wp;  wp += (size_t)BATCH * NGRP * sizeof(vf4);   // 16 KB
    int* counts  = (int*)wp;  wp += (size_t)BATCH * NCELL * 4;            // 128 KB
    int* cursor  = (int*)wp;  wp += (size_t)BATCH * NCELL * 4;            // 128 KB
    float* pts_ws = (float*)wp; wp += (size_t)BATCH * SCH * 3 * 4;
    int*   idx_ws = (int*)wp;   wp += (size_t)BATCH * SCH * 4;
    int*   grp_ws = (int*)wp;   wp += (size_t)BATCH * SCH * KNN * 4;      // 1 MB
    int*   conv_ws = (int*)wp;

    hipMemsetAsync(counts, 0, (size_t)BATCH * NCELL * 4, stream);
    prep_kernel<<<(BATCH * NPTS + 255) / 256, 256, 0, stream>>>(xyz, pc4, counts);
    scan_kernel<<<BATCH, 1024, 0, stream>>>(counts, cursor);
    scatter_kernel<<<(BATCH * NPTS + 255) / 256, 256, 0, stream>>>(pc4, cursor, sortedP);
    bbox_kernel<<<(BATCH * NGRP * 64) / 256, 256, 0, stream>>>(sortedP, bC, bH);

    const int chains = BATCH * SCH;                 // 8192 waves, 1 per chain
    refine_kernel<<<chains * 64 / 256, 256, 0, stream>>>(
        pc4, sortedP, bC, bH, center, idx_in, pts_ws, idx_ws, grp_ws, conv_ws);
    order_kernel<<<BATCH, SCH, 0, stream>>>(pts_ws, idx_ws, grp_ws, conv_ws, out);
}